// Round 17
// baseline (1582.842 us; speedup 1.0000x reference)
//
#include <hip/hip_runtime.h>

// FlowNetC correlation: B=8, C=128, H=128, W=256, PAD=4, MD=4, K=1, S1=S2=1
// out[b, dyi*9+dxi, h, w] = (1/128) * sum_c in1[b,c,h,w] * in2[b,c,h+dyi-4,w+dxi-4]
// (in2 zero outside bounds)
//
// R8: depth-3 register pipeline on the R5 structure (single change vs R5).
// Ledger: R4 247us/VALU23%; R5 252us/VALU54% (depth-2); R6 depth-4 spilled
// (needed ~130 VGPR > 128 cap -> 7GB scratch, 1805us); R7 LDS-staging 365us
// (42M LDS bank-conflict cy, 25% VALU — staging funnels the same 4 ops/ch
// through one CU's LDS at 1.2 blocks/CU; L2-redundancy NOT the wall).
// Remaining theory: loads miss L2 (temporal reuse scattered) -> ~LLC latency
// ~450-600cy; depth-2 tolerance ~2x224 own-cycles just misses -> 46% stall.
// Depth-3: 3 sets x 16 + acc 36 + addr ~14 = ~105 VGPR < 128 -> fits (256,4).
//  - wave = one (b, h, dy) output row: 64 lanes x 4 px; 9216 waves.
//  - per channel: 1 in1 float4 + 3 in2 float4 (w0-4, w0, w0+4), all aligned.
//  - edge lanes clamp; garbage feeds only epilogue-killed acc entries.
// XCD swizzle: 2304 blocks = 8 XCD x 288; XCD x owns exactly b = x.

#define NC 128
#define NH 128
#define NW 256
#define ND 9
#define CH 32768                 // NH*NW floats = channel stride
#define SCALE (1.0f / 128.0f)

// snapshot set k (channel c), issue loads for channel c+3 into set k, FMA
#define PHASE(k)                                                          \
    {                                                                     \
        const float a_[4]  = {A##k.x, A##k.y, A##k.z, A##k.w};            \
        const float bw[12] = {P##k.x, P##k.y, P##k.z, P##k.w,             \
                              Q##k.x, Q##k.y, Q##k.z, Q##k.w,             \
                              R##k.x, R##k.y, R##k.z, R##k.w};            \
        A##k = *(const float4*)(pa + oa);                                 \
        P##k = *(const float4*)(pb + ob0);                                \
        Q##k = *(const float4*)(pb + ob1);                                \
        R##k = *(const float4*)(pb + ob2);                                \
        oa += CH; ob0 += CH; ob1 += CH; ob2 += CH;                        \
        _Pragma("unroll")                                                 \
        for (int p = 0; p < 4; ++p)                                       \
            _Pragma("unroll")                                             \
            for (int d = 0; d < ND; ++d)                                  \
                acc[p][d] += a_[p] * bw[p + d];                           \
    }

// compute-only (tail): no further loads
#define PHASE_TAIL(k)                                                     \
    {                                                                     \
        const float a_[4]  = {A##k.x, A##k.y, A##k.z, A##k.w};            \
        const float bw[12] = {P##k.x, P##k.y, P##k.z, P##k.w,             \
                              Q##k.x, Q##k.y, Q##k.z, Q##k.w,             \
                              R##k.x, R##k.y, R##k.z, R##k.w};            \
        _Pragma("unroll")                                                 \
        for (int p = 0; p < 4; ++p)                                       \
            _Pragma("unroll")                                             \
            for (int d = 0; d < ND; ++d)                                  \
                acc[p][d] += a_[p] * bw[p + d];                           \
    }

#define LOAD_SET(k)                                                       \
    A##k = *(const float4*)(pa + oa);                                     \
    P##k = *(const float4*)(pb + ob0);                                    \
    Q##k = *(const float4*)(pb + ob1);                                    \
    R##k = *(const float4*)(pb + ob2);                                    \
    oa += CH; ob0 += CH; ob1 += CH; ob2 += CH;

__global__ __launch_bounds__(256, 4) void corr_kernel(
    const float* __restrict__ in1, const float* __restrict__ in2,
    float* __restrict__ out)
{
    const int bid = blockIdx.x;
    const int sid = (bid & 7) * 288 + (bid >> 3);     // XCD-contiguous
    const int id  = sid * 4 + (threadIdx.x >> 6);     // 0..9215
    const int g   = threadIdx.x & 63;

    const int dyi  = id % ND;
    const int rest = id / ND;        // 0..1023
    const int h    = rest & 127;
    const int b    = rest >> 7;

    const int w0 = g << 2;           // 4 px per lane: w0..w0+3
    const int hh = h + dyi - 4;      // in2 source row (wave-uniform)
    const bool valid = ((unsigned)hh < (unsigned)NH);
    const int hhc = valid ? hh : 0;

    const float* __restrict__ pa = in1 + (size_t)(b * NC * NH + h)   * NW;
    const float* __restrict__ pb = in2 + (size_t)(b * NC * NH + hhc) * NW;

    // 32-bit running offsets (max 127*32768+259 < 2^23)
    int oa  = w0;
    int ob0 = (g == 0)  ? 0  : (w0 - 4);   // bw[0..3]  = in2[w0-4..w0-1]
    int ob1 = w0;                          // bw[4..7]  = in2[w0..w0+3]
    int ob2 = (g == 63) ? w0 : (w0 + 4);   // bw[8..11] = in2[w0+4..w0+7]

    float acc[4][ND];
#pragma unroll
    for (int p = 0; p < 4; ++p)
#pragma unroll
        for (int d = 0; d < ND; ++d) acc[p][d] = 0.f;

    // prologue: load channels 0,1,2 into sets 0,1,2
    float4 A0, P0, Q0, R0;
    float4 A1, P1, Q1, R1;
    float4 A2, P2, Q2, R2;
    LOAD_SET(0)
    LOAD_SET(1)
    LOAD_SET(2)

    // main loop: 41 iters x 3 = channels 0..122 computed, 3..125 loaded
#pragma unroll 1
    for (int c = 0; c < 123; c += 3) {
        PHASE(0)
        PHASE(1)
        PHASE(2)
    }
    PHASE(0)        // compute ch123, load ch126
    PHASE(1)        // compute ch124, load ch127
    PHASE_TAIL(2)   // ch125
    PHASE_TAIL(0)   // ch126
    PHASE_TAIL(1)   // ch127

    // epilogue: zero entries whose in2 sample is out of bounds, scale, store
    float* outp = out + ((size_t)(b * (ND * ND) + dyi * ND) * NH + h) * NW + w0;
#pragma unroll
    for (int d = 0; d < ND; ++d) {
        float v[4];
#pragma unroll
        for (int p = 0; p < 4; ++p) {
            const bool kill = (!valid) ||
                              (g == 0  && (p + d) < 4) ||   // w-sample < 0
                              (g == 63 && (p + d) > 7);     // w-sample > 255
            v[p] = kill ? 0.0f : acc[p][d] * SCALE;
        }
        float4 o4 = {v[0], v[1], v[2], v[3]};
        *(float4*)(outp + (size_t)d * CH) = o4;
    }
}

extern "C" void kernel_launch(void* const* d_in, const int* in_sizes, int n_in,
                              void* d_out, int out_size, void* d_ws, size_t ws_size,
                              hipStream_t stream) {
    const float* in1 = (const float*)d_in[0];
    const float* in2 = (const float*)d_in[1];
    float* out = (float*)d_out;
    corr_kernel<<<dim3(2304), dim3(256), 0, stream>>>(in1, in2, out);
}

// Round 18
// 458.309 us; speedup vs baseline: 3.4537x; 3.4537x over previous
//
#include <hip/hip_runtime.h>

// FlowNetC correlation: B=8, C=128, H=128, W=256, PAD=4, MD=4, K=1, S1=S2=1
// out[b, dyi*9+dxi, h, w] = (1/128) * sum_c in1[b,c,h,w] * in2[b,c,h+dyi-4,w+dxi-4]
// (in2 zero outside bounds)
//
// R9: depth-3 + launch_bounds(256,2) + direct-consume phases.
// Ledger: R4 247us/VALU23% (depth-1ish); R5 252us/VALU54% (depth-2);
// R6 depth-4 SPILL (7GB scratch, 1805us); R7 LDS-staging 365us (bank-conflict
// + barrier wall; L2-redundancy refuted); R8 depth-3 SPILL (5GB, 1403us).
// Every family member reports VGPR_Count=64 -> the (256,4) launch bound caps
// the allocator at 64 arch-VGPRs; depth>=3 (~105 live) spills to scratch.
// Fixes: (1) launch_bounds(256,2) raises the cap to >=256 so the allocator
// can hold 3 in-flight sets; HW occupancy stays 4 waves/SIMD if final count
// <=128. (2) phases FMA-then-reload (no snapshot copies, no read-after-
// overwrite hazard); depth-3 puts 2 compute phases between load and use.
//  - wave = one (b, h, dy) output row: 64 lanes x 4 px; 9216 waves.
//  - per channel: 1 in1 float4 + 3 in2 float4 (w0-4, w0, w0+4), all aligned.
//  - edge lanes clamp; garbage feeds only epilogue-killed acc entries.
// XCD swizzle: 2304 blocks = 8 XCD x 288; XCD x owns exactly b = x.

#define NC 128
#define NH 128
#define NW 256
#define ND 9
#define CH 32768                 // NH*NW floats = channel stride
#define SCALE (1.0f / 128.0f)

// FMA from set k (channel c), THEN issue loads for channel c+3 into set k.
#define PHASE(k)                                                          \
    {                                                                     \
        const float a_[4]  = {A##k.x, A##k.y, A##k.z, A##k.w};            \
        const float bw[12] = {P##k.x, P##k.y, P##k.z, P##k.w,             \
                              Q##k.x, Q##k.y, Q##k.z, Q##k.w,             \
                              R##k.x, R##k.y, R##k.z, R##k.w};            \
        _Pragma("unroll")                                                 \
        for (int p = 0; p < 4; ++p)                                       \
            _Pragma("unroll")                                             \
            for (int d = 0; d < ND; ++d)                                  \
                acc[p][d] += a_[p] * bw[p + d];                           \
        A##k = *(const float4*)(pa + oa);                                 \
        P##k = *(const float4*)(pb + ob0);                                \
        Q##k = *(const float4*)(pb + ob1);                                \
        R##k = *(const float4*)(pb + ob2);                                \
        oa += CH; ob0 += CH; ob1 += CH; ob2 += CH;                        \
    }

// compute-only (tail): no further loads
#define PHASE_TAIL(k)                                                     \
    {                                                                     \
        const float a_[4]  = {A##k.x, A##k.y, A##k.z, A##k.w};            \
        const float bw[12] = {P##k.x, P##k.y, P##k.z, P##k.w,             \
                              Q##k.x, Q##k.y, Q##k.z, Q##k.w,             \
                              R##k.x, R##k.y, R##k.z, R##k.w};            \
        _Pragma("unroll")                                                 \
        for (int p = 0; p < 4; ++p)                                       \
            _Pragma("unroll")                                             \
            for (int d = 0; d < ND; ++d)                                  \
                acc[p][d] += a_[p] * bw[p + d];                           \
    }

#define LOAD_SET(k)                                                       \
    A##k = *(const float4*)(pa + oa);                                     \
    P##k = *(const float4*)(pb + ob0);                                    \
    Q##k = *(const float4*)(pb + ob1);                                    \
    R##k = *(const float4*)(pb + ob2);                                    \
    oa += CH; ob0 += CH; ob1 += CH; ob2 += CH;

__global__ __launch_bounds__(256, 2) void corr_kernel(
    const float* __restrict__ in1, const float* __restrict__ in2,
    float* __restrict__ out)
{
    const int bid = blockIdx.x;
    const int sid = (bid & 7) * 288 + (bid >> 3);     // XCD-contiguous
    const int id  = sid * 4 + (threadIdx.x >> 6);     // 0..9215
    const int g   = threadIdx.x & 63;

    const int dyi  = id % ND;
    const int rest = id / ND;        // 0..1023
    const int h    = rest & 127;
    const int b    = rest >> 7;

    const int w0 = g << 2;           // 4 px per lane: w0..w0+3
    const int hh = h + dyi - 4;      // in2 source row (wave-uniform)
    const bool valid = ((unsigned)hh < (unsigned)NH);
    const int hhc = valid ? hh : 0;

    const float* __restrict__ pa = in1 + (size_t)(b * NC * NH + h)   * NW;
    const float* __restrict__ pb = in2 + (size_t)(b * NC * NH + hhc) * NW;

    // 32-bit running offsets (max in-loop deref 127*32768+259 < 2^23)
    int oa  = w0;
    int ob0 = (g == 0)  ? 0  : (w0 - 4);   // bw[0..3]  = in2[w0-4..w0-1]
    int ob1 = w0;                          // bw[4..7]  = in2[w0..w0+3]
    int ob2 = (g == 63) ? w0 : (w0 + 4);   // bw[8..11] = in2[w0+4..w0+7]

    float acc[4][ND];
#pragma unroll
    for (int p = 0; p < 4; ++p)
#pragma unroll
        for (int d = 0; d < ND; ++d) acc[p][d] = 0.f;

    // prologue: load channels 0,1,2 into sets 0,1,2
    float4 A0, P0, Q0, R0;
    float4 A1, P1, Q1, R1;
    float4 A2, P2, Q2, R2;
    LOAD_SET(0)
    LOAD_SET(1)
    LOAD_SET(2)

    // main loop: 41 iters x 3 = channels 0..122 computed, 3..125 loaded
#pragma unroll 1
    for (int c = 0; c < 123; c += 3) {
        PHASE(0)
        PHASE(1)
        PHASE(2)
    }
    PHASE(0)        // compute ch123, load ch126
    PHASE(1)        // compute ch124, load ch127
    PHASE_TAIL(2)   // ch125
    PHASE_TAIL(0)   // ch126
    PHASE_TAIL(1)   // ch127

    // epilogue: zero entries whose in2 sample is out of bounds, scale, store
    float* outp = out + ((size_t)(b * (ND * ND) + dyi * ND) * NH + h) * NW + w0;
#pragma unroll
    for (int d = 0; d < ND; ++d) {
        float v[4];
#pragma unroll
        for (int p = 0; p < 4; ++p) {
            const bool kill = (!valid) ||
                              (g == 0  && (p + d) < 4) ||   // w-sample < 0
                              (g == 63 && (p + d) > 7);     // w-sample > 255
            v[p] = kill ? 0.0f : acc[p][d] * SCALE;
        }
        float4 o4 = {v[0], v[1], v[2], v[3]};
        *(float4*)(outp + (size_t)d * CH) = o4;
    }
}

extern "C" void kernel_launch(void* const* d_in, const int* in_sizes, int n_in,
                              void* d_out, int out_size, void* d_ws, size_t ws_size,
                              hipStream_t stream) {
    const float* in1 = (const float*)d_in[0];
    const float* in2 = (const float*)d_in[1];
    float* out = (float*)d_out;
    corr_kernel<<<dim3(2304), dim3(256), 0, stream>>>(in1, in2, out);
}

// Round 22
// 384.971 us; speedup vs baseline: 4.1116x; 1.1905x over previous
//
#include <hip/hip_runtime.h>

// FlowNetC correlation: B=8, C=128, H=128, W=256, PAD=4, MD=4, K=1, S1=S2=1
// out[b, dyi*9+dxi, h, w] = (1/128) * sum_c in1[b,c,h,w] * in2[b,c,h+dyi-4,w+dxi-4]
// (in2 zero outside bounds)
//
// R10 (4th submit; infra flake, never measured): halve L1-miss traffic.
// Ledger: R4 247us (8px,6ld,d1,VALU23%); R5 252us (4px,4ld,d2,VALU54%);
// R9 273us (d3,(256,2),VGPR88,VALU55%); R6/R8 spills; R7 LDS 365us (bank
// conflicts+barriers). Depth x occupancy x VALU all varied -> time pinned
// ~250us => model: per-CU L1-miss service rate (MSHR x latency) on ~all-miss
// traffic. Lever: fewer wave-loads. 8px/lane (72 FMA/ch) + shuffle edge
// words => 4 loads/ch, 2.36M wave-loads (half of R5). Depth-2 E/O,
// direct-consume phases (R9 pattern).
//  - wave = (b, h-pair, dy): 64 lanes = 2 rows x 32 lanes x 8px.
//  - per ch: A0,A1 = in1[w0..w0+7]; B1,B2 = in2[w0..w0+7];
//    bw[0..3] = lane g-1's B2 (= in2[w0-4..w0-1]), bw[12..15] = lane g+1's B1.
//    Cross-row/wave shuffle garbage feeds only epilogue-killed acc entries.
// XCD swizzle: 1152 blocks = 8 XCD x 144; XCD x owns exactly b = x.

#define NC 128
#define NH 128
#define NW 256
#define ND 9
#define CH 32768                 // NH*NW floats = channel stride
#define SCALE (1.0f / 128.0f)

__global__ __launch_bounds__(256, 2) void corr_kernel(
    const float* __restrict__ in1, const float* __restrict__ in2,
    float* __restrict__ out)
{
    const int bid = blockIdx.x;
    const int id  = ((bid & 7) * 144 + (bid >> 3)) * 4 + (threadIdx.x >> 6);
    const int g   = threadIdx.x & 63;

    const int dyi  = id % ND;
    const int rest = id / ND;        // 0..511
    const int hp   = rest & 63;
    const int b    = rest >> 6;

    const int r  = g >> 5;           // sub-row 0/1
    const int L  = g & 31;           // lane within row
    const int w0 = L << 3;           // 8 px per lane
    const int h  = (hp << 1) + r;
    const int hh = h + dyi - 4;      // in2 source row (per-lane via r)
    const bool valid = ((unsigned)hh < (unsigned)NH);
    const int hhc = valid ? hh : 0;

    const float* __restrict__ pa = in1 + (size_t)(b * NC * NH + h)   * NW;
    const float* __restrict__ pb = in2 + (size_t)(b * NC * NH + hhc) * NW;
    int oa = w0;                     // shared column offset, advances by CH

    float acc[8][ND];
#pragma unroll
    for (int p = 0; p < 8; ++p)
#pragma unroll
        for (int d = 0; d < ND; ++d) acc[p][d] = 0.f;

    // prologue: channel 0 -> E set, channel 1 -> O set
    float4 A0e = *(const float4*)(pa + oa);
    float4 A1e = *(const float4*)(pa + oa + 4);
    float4 B1e = *(const float4*)(pb + oa);
    float4 B2e = *(const float4*)(pb + oa + 4);
    oa += CH;
    float4 A0o = *(const float4*)(pa + oa);
    float4 A1o = *(const float4*)(pa + oa + 4);
    float4 B1o = *(const float4*)(pb + oa);
    float4 B2o = *(const float4*)(pb + oa + 4);
    oa += CH;

    // phase: shuffles -> FMA -> reload set (direct-consume, low peak VGPR)
#define PHASE(S)                                                            \
    {                                                                       \
        const float e0x = __shfl(B2##S.x, g - 1);                           \
        const float e0y = __shfl(B2##S.y, g - 1);                           \
        const float e0z = __shfl(B2##S.z, g - 1);                           \
        const float e0w = __shfl(B2##S.w, g - 1);                           \
        const float e3x = __shfl(B1##S.x, g + 1);                           \
        const float e3y = __shfl(B1##S.y, g + 1);                           \
        const float e3z = __shfl(B1##S.z, g + 1);                           \
        const float e3w = __shfl(B1##S.w, g + 1);                           \
        const float a_[8]  = {A0##S.x, A0##S.y, A0##S.z, A0##S.w,           \
                              A1##S.x, A1##S.y, A1##S.z, A1##S.w};          \
        const float bw[16] = {e0x, e0y, e0z, e0w,                           \
                              B1##S.x, B1##S.y, B1##S.z, B1##S.w,           \
                              B2##S.x, B2##S.y, B2##S.z, B2##S.w,           \
                              e3x, e3y, e3z, e3w};                          \
        _Pragma("unroll")                                                   \
        for (int p = 0; p < 8; ++p)                                         \
            _Pragma("unroll")                                               \
            for (int d = 0; d < ND; ++d)                                    \
                acc[p][d] += a_[p] * bw[p + d];                             \
        A0##S = *(const float4*)(pa + oa);                                  \
        A1##S = *(const float4*)(pa + oa + 4);                              \
        B1##S = *(const float4*)(pb + oa);                                  \
        B2##S = *(const float4*)(pb + oa + 4);                              \
        oa += CH;                                                           \
    }

#define PHASE_TAIL(S)                                                       \
    {                                                                       \
        const float e0x = __shfl(B2##S.x, g - 1);                           \
        const float e0y = __shfl(B2##S.y, g - 1);                           \
        const float e0z = __shfl(B2##S.z, g - 1);                           \
        const float e0w = __shfl(B2##S.w, g - 1);                           \
        const float e3x = __shfl(B1##S.x, g + 1);                           \
        const float e3y = __shfl(B1##S.y, g + 1);                           \
        const float e3z = __shfl(B1##S.z, g + 1);                           \
        const float e3w = __shfl(B1##S.w, g + 1);                           \
        const float a_[8]  = {A0##S.x, A0##S.y, A0##S.z, A0##S.w,           \
                              A1##S.x, A1##S.y, A1##S.z, A1##S.w};          \
        const float bw[16] = {e0x, e0y, e0z, e0w,                           \
                              B1##S.x, B1##S.y, B1##S.z, B1##S.w,           \
                              B2##S.x, B2##S.y, B2##S.z, B2##S.w,           \
                              e3x, e3y, e3z, e3w};                          \
        _Pragma("unroll")                                                   \
        for (int p = 0; p < 8; ++p)                                         \
            _Pragma("unroll")                                               \
            for (int d = 0; d < ND; ++d)                                    \
                acc[p][d] += a_[p] * bw[p + d];                             \
    }

    // main loop: 63 iters; E consumes ch c (loads c+2), O consumes c+1
    // (loads c+3). After c=124: E holds 126, O holds 127.
#pragma unroll 1
    for (int c = 0; c < 126; c += 2) {
        PHASE(e)
        PHASE(o)
    }
    PHASE_TAIL(e)   // ch 126
    PHASE_TAIL(o)   // ch 127

#undef PHASE
#undef PHASE_TAIL

    // epilogue: zero entries whose in2 sample is out of bounds, scale, store
    float* outp = out + ((size_t)(b * (ND * ND) + dyi * ND) * NH + h) * NW + w0;
#pragma unroll
    for (int d = 0; d < ND; ++d) {
        float v[8];
#pragma unroll
        for (int p = 0; p < 8; ++p) {
            const bool kill = (!valid) ||
                              (L == 0  && (p + d) < 4) ||    // w-sample < 0
                              (L == 31 && (p + d) > 11);     // w-sample > 255
            v[p] = kill ? 0.0f : acc[p][d] * SCALE;
        }
        float4 lo = {v[0], v[1], v[2], v[3]};
        float4 hi = {v[4], v[5], v[6], v[7]};
        *(float4*)(outp + (size_t)d * CH)     = lo;
        *(float4*)(outp + (size_t)d * CH + 4) = hi;
    }
}

extern "C" void kernel_launch(void* const* d_in, const int* in_sizes, int n_in,
                              void* d_out, int out_size, void* d_ws, size_t ws_size,
                              hipStream_t stream) {
    const float* in1 = (const float*)d_in[0];
    const float* in2 = (const float*)d_in[1];
    float* out = (float*)d_out;
    corr_kernel<<<dim3(1152), dim3(256), 0, stream>>>(in1, in2, out);
}